// Round 2
// baseline (1468.436 us; speedup 1.0000x reference)
//
#include <hip/hip_runtime.h>
#include <cmath>

// ---------------- elementwise / setup ----------------
__global__ void k_count_deg(const int* __restrict__ dst, float* __restrict__ deg, int E){
  int e = blockIdx.x*256 + threadIdx.x;
  if(e<E) atomicAdd(&deg[dst[e]], 1.0f);
}

__global__ void k_finish_dinv(float* __restrict__ d, int n){
  int i = blockIdx.x*256 + threadIdx.x;
  if(i<n) d[i] = rsqrtf(d[i] + 1.0f);   // deg includes +1 self loop
}

// ---------------- GEMM: out(fp32[M,Nc]) = A(fp32[M,K]) @ B(fp32[K,Nc]) ----------------
// M%64==0, Nc%64==0, K%16==0. block 16x16, 64x64 tile, 4x4 per thread.
__global__ void k_gemm(const float* __restrict__ A, const float* __restrict__ B,
                       float* __restrict__ C, int M, int K, int Nc){
  __shared__ float As[16][65];  // As[k][m]
  __shared__ float Bs[16][65];  // Bs[k][n]
  const int tx = threadIdx.x, ty = threadIdx.y;
  const int tid = ty*16 + tx;
  const int row0 = blockIdx.y*64, col0 = blockIdx.x*64;
  float acc[4][4] = {};
  for(int kt=0; kt<K; kt+=16){
    #pragma unroll
    for(int i=0;i<4;i++){
      int idx = i*256 + tid;
      As[idx & 15][idx >> 4] = A[(size_t)(row0 + (idx>>4))*K + kt + (idx&15)];
    }
    #pragma unroll
    for(int i=0;i<4;i++){
      int idx = i*256 + tid;
      Bs[idx >> 6][idx & 63] = B[(size_t)(kt + (idx>>6))*Nc + col0 + (idx&63)];
    }
    __syncthreads();
    #pragma unroll
    for(int k=0;k<16;k++){
      float a[4], b[4];
      #pragma unroll
      for(int i=0;i<4;i++) a[i] = As[k][ty*4+i];
      #pragma unroll
      for(int j=0;j<4;j++) b[j] = Bs[k][tx*4+j];
      #pragma unroll
      for(int i=0;i<4;i++)
        #pragma unroll
        for(int j=0;j<4;j++) acc[i][j] += a[i]*b[j];
    }
    __syncthreads();
  }
  #pragma unroll
  for(int i=0;i<4;i++){
    size_t r = (size_t)(row0 + ty*4 + i);
    #pragma unroll
    for(int j=0;j<4;j++)
      C[r*Nc + col0 + tx*4 + j] = acc[i][j];
  }
}

// ---------------- sparse GCN aggregation (C == 128) ----------------
// out[n,c] = hW[n,c]*dinv[n]^2 + bias[c]   (self-loop + bias init)
__global__ void k_agg_init(const float* __restrict__ hW, const float* __restrict__ dinv,
                           const float* __restrict__ bias, float* __restrict__ out, int n){
  int i = blockIdx.x*256 + threadIdx.x;
  if(i<n){
    float dv = dinv[i>>7];
    out[i] = hW[i]*dv*dv + bias[i & 127];
  }
}

// out[dst,c] += hW[src,c]*dinv[src]*dinv[dst]   (one block per edge, 128 ch)
__global__ void k_agg_edges(const int* __restrict__ src, const int* __restrict__ dst,
                            const float* __restrict__ dinv, const float* __restrict__ hW,
                            float* __restrict__ out, int E){
  int e = blockIdx.x;
  int c = threadIdx.x;
  int s = src[e], d = dst[e];
  float coef = dinv[s]*dinv[d];
  atomicAdd(&out[(size_t)d*128 + c], hW[(size_t)s*128 + c]*coef);
}

// t[dst,c] += s[src,c]  (un-normalized A @ s)
__global__ void k_t_edges(const int* __restrict__ src, const int* __restrict__ dst,
                          const float* __restrict__ sM, float* __restrict__ t, int E){
  int e = blockIdx.x;
  int c = threadIdx.x;
  atomicAdd(&t[(size_t)dst[e]*128 + c], sM[(size_t)src[e]*128 + c]);
}

// ---------------- BatchNorm (C == 128) ----------------
// stride and block base are multiples of 128 -> each thread sees a single channel (t & 127)
__global__ void k_bn_stats(const float* __restrict__ x, float* __restrict__ gsum,
                           float* __restrict__ gsqs, int n){
  __shared__ float ss[256], sq[256];
  int t = threadIdx.x;
  float s0 = 0.f, q0 = 0.f;
  for(int i = blockIdx.x*256 + t; i < n; i += gridDim.x*256){
    float v = x[i];
    s0 += v; q0 += v*v;
  }
  ss[t] = s0; sq[t] = q0;
  __syncthreads();
  if(t < 128){
    atomicAdd(&gsum[t], ss[t] + ss[t+128]);
    atomicAdd(&gsqs[t], sq[t] + sq[t+128]);
  }
}

// out = (res? res:0) + silu(g*(x-m)*rsqrt(v+eps)+be)
__global__ void k_bn_apply(const float* __restrict__ x, const float* __restrict__ res,
                           const float* __restrict__ gsum, const float* __restrict__ gsqs,
                           const float* __restrict__ gamma, const float* __restrict__ beta,
                           float* __restrict__ out, int n, float invM){
  int i = blockIdx.x*256 + threadIdx.x;
  if(i<n){
    int c = i & 127;
    float m = gsum[c]*invM;
    float v = gsqs[c]*invM - m*m;
    float xh = (x[i]-m)*rsqrtf(v + 1e-5f);
    float y = gamma[c]*xh + beta[c];
    y = y / (1.f + __expf(-y));
    out[i] = (res ? res[i] : 0.f) + y;
  }
}

// ---------------- softmax over rows of 128, in place; wave per row ----------------
__global__ void k_softmax128(float* __restrict__ x, int rows){
  int wave = (blockIdx.x*blockDim.x + threadIdx.x) >> 6;
  int lane = threadIdx.x & 63;
  if(wave >= rows) return;
  float* r = x + (size_t)wave*128;
  float a = r[lane], b = r[lane+64];
  float mx = fmaxf(a,b);
  #pragma unroll
  for(int o=32;o>0;o>>=1) mx = fmaxf(mx, __shfl_xor(mx, o));
  float ea = __expf(a-mx), eb = __expf(b-mx);
  float s = ea+eb;
  #pragma unroll
  for(int o=32;o>0;o>>=1) s += __shfl_xor(s, o);
  float inv = 1.f/s;
  r[lane] = ea*inv; r[lane+64] = eb*inv;
}

// ---------------- pooled gemm: out[b,i,j] = sum_n P[b,n,i]*Q[b,n,j], P/Q rows [b*npg+n, 128] ----------------
__global__ void k_pool_gemm(const float* __restrict__ P, const float* __restrict__ Q,
                            float* __restrict__ out, int npg){
  __shared__ float Ps[16][17], Qs[16][17];
  int b = blockIdx.z;
  int i0 = blockIdx.y*16, j0 = blockIdx.x*16;
  int tx = threadIdx.x, ty = threadIdx.y;
  const float* Pb = P + (size_t)b*npg*128;
  const float* Qb = Q + (size_t)b*npg*128;
  float acc = 0.f;
  for(int n0=0; n0<npg; n0+=16){
    Ps[ty][tx] = Pb[(size_t)(n0+ty)*128 + i0 + tx];
    Qs[ty][tx] = Qb[(size_t)(n0+ty)*128 + j0 + tx];
    __syncthreads();
    #pragma unroll
    for(int k=0;k<16;k++) acc += Ps[k][ty]*Qs[k][tx];
    __syncthreads();
  }
  out[((size_t)b*128 + i0+ty)*128 + j0+tx] = acc;
}

// ---------------- dense stage ----------------
__global__ void k_dinv2(const float* __restrict__ A2, float* __restrict__ dinv2, int rows){
  int r = blockIdx.x;
  int t = threadIdx.x;               // 128
  float v = A2[(size_t)r*128 + t];
  #pragma unroll
  for(int o=32;o>0;o>>=1) v += __shfl_xor(v, o);
  __shared__ float w[2];
  if((t & 63) == 0) w[t>>6] = v;
  __syncthreads();
  if(t==0) dinv2[r] = rsqrtf(w[0] + w[1] + 1.0f);
}

__global__ void k_scale_rows(float* __restrict__ x, const float* __restrict__ dinv2, int n){
  int i = blockIdx.x*256 + threadIdx.x;
  if(i<n) x[i] *= dinv2[i>>7];
}

// out[b] = A2[b](128x128) @ X[b](128x128); block 16x16, grid (8,8,B)
__global__ void k_bgemm(const float* __restrict__ A, const float* __restrict__ X,
                        float* __restrict__ out){
  __shared__ float As[16][17], Xs[16][17];
  int b = blockIdx.z;
  int i0 = blockIdx.y*16, j0 = blockIdx.x*16;
  int tx = threadIdx.x, ty = threadIdx.y;
  const float* Ab = A + (size_t)b*128*128;
  const float* Xb = X + (size_t)b*128*128;
  float acc = 0.f;
  for(int k0=0;k0<128;k0+=16){
    As[ty][tx] = Ab[(i0+ty)*128 + k0+tx];
    Xs[ty][tx] = Xb[(k0+ty)*128 + j0+tx];
    __syncthreads();
    #pragma unroll
    for(int k=0;k<16;k++) acc += As[ty][k]*Xs[k][tx];
    __syncthreads();
  }
  out[((size_t)b*128 + i0+ty)*128 + j0+tx] = acc;
}

// tmp = dinv2[r]*(tmp + hws) + bias[c]
__global__ void k_dense_post(float* __restrict__ tmp, const float* __restrict__ hws,
                             const float* __restrict__ dinv2, const float* __restrict__ bias,
                             int n){
  int i = blockIdx.x*256 + threadIdx.x;
  if(i<n){
    tmp[i] = dinv2[i>>7]*(tmp[i] + hws[i]) + bias[i & 127];
  }
}

// ---------------- final: g = (1/K2) sum_n h2[b,n,:]; out = log_softmax(g@wl + bl) ----------------
__global__ void k_final(const float* __restrict__ h2, const float* __restrict__ wl,
                        const float* __restrict__ bl, float* __restrict__ out,
                        int K1n, int Cc, int OUTc, float inv_k2, int zero_idx){
  int b = blockIdx.x;
  int t = threadIdx.x;                // 128 threads
  __shared__ float g[128];
  __shared__ float logits[32];
  __shared__ float mred, lred;
  const float* hb = h2 + (size_t)b*K1n*Cc;
  float acc = 0.f;
  for(int n=0;n<K1n;n++) acc += hb[(size_t)n*Cc + t];
  g[t] = acc * inv_k2;
  __syncthreads();
  if(t < OUTc){
    float l = bl[t];
    for(int d=0; d<Cc; d++) l += g[d]*wl[d*OUTc + t];
    logits[t] = l;
  }
  __syncthreads();
  if(t==0){
    float m = -1e30f;
    for(int o=0;o<OUTc;o++) m = fmaxf(m, logits[o]);
    float s = 0.f;
    for(int o=0;o<OUTc;o++) s += __expf(logits[o]-m);
    mred = m; lred = logf(s);
  }
  __syncthreads();
  if(t < OUTc) out[b*OUTc + t] = logits[t] - mred - lred;
  if(b==0 && t==0 && zero_idx >= 0) out[zero_idx] = 0.f;
}

// ---------------- launch ----------------
extern "C" void kernel_launch(void* const* d_in, const int* in_sizes, int n_in,
                              void* d_out, int out_size, void* d_ws, size_t ws_size,
                              hipStream_t stream){
  const float* x    = (const float*)d_in[0];
  const int*   ei   = (const int*)d_in[1];
  const float* w1a  = (const float*)d_in[4];
  const float* b1a  = (const float*)d_in[5];
  const float* g1a  = (const float*)d_in[6];
  const float* be1a = (const float*)d_in[7];
  const float* w1b  = (const float*)d_in[8];
  const float* b1b  = (const float*)d_in[9];
  const float* g1b  = (const float*)d_in[10];
  const float* be1b = (const float*)d_in[11];
  const float* wp1  = (const float*)d_in[12];
  const float* bp1  = (const float*)d_in[13];
  const float* w2a  = (const float*)d_in[14];
  const float* b2a  = (const float*)d_in[15];
  const float* g2a  = (const float*)d_in[16];
  const float* be2a = (const float*)d_in[17];
  const float* w2b  = (const float*)d_in[18];
  const float* b2b  = (const float*)d_in[19];
  const float* g2b  = (const float*)d_in[20];
  const float* be2b = (const float*)d_in[21];
  const float* wl   = (const float*)d_in[24];
  const float* bl   = (const float*)d_in[25];
  float* out = (float*)d_out;

  const int C_   = in_sizes[5];            // 128
  const int CIN_ = in_sizes[4]/C_;         // 64
  const int N    = in_sizes[0]/CIN_;       // 32768
  const int E    = in_sizes[1]/2;          // 524288
  const int B_   = in_sizes[3]-1;          // 32
  const int NPG_ = N/B_;                   // 1024
  const int K1_  = in_sizes[13];           // 128
  const int K2_  = in_sizes[23];           // 32
  const int OUTc = in_sizes[25];           // 10
  const int M2   = B_*K1_;                 // 4096

  const int* srcI = ei;
  const int* dstI = ei + E;

  float* ws = (float*)d_ws;
  size_t o = 0;
  float* dinv  = ws + o; o += (size_t)N;
  float* bufW  = ws + o; o += (size_t)N*C_;
  float* bufA  = ws + o; o += (size_t)N*C_;
  float* bufB  = ws + o; o += (size_t)N*C_;
  float* x2    = ws + o; o += (size_t)M2*C_;
  float* A2    = ws + o; o += (size_t)M2*K1_;
  float* dinv2 = ws + o; o += (size_t)M2;
  float* dW    = ws + o; o += (size_t)M2*C_;
  float* dT    = ws + o; o += (size_t)M2*C_;
  float* h2a   = ws + o; o += (size_t)M2*C_;
  float* h2b   = ws + o; o += (size_t)M2*C_;
  float* gsum  = ws + o; o += (size_t)C_;
  float* gsqs  = ws + o; o += (size_t)C_;
  (void)ws_size; (void)n_in;

  dim3 blk256(256);
  dim3 gblk(16,16);
  auto g1 = [](int n){ return dim3((unsigned)((n+255)/256)); };

  // degrees -> dinv
  hipMemsetAsync(dinv, 0, (size_t)N*sizeof(float), stream);
  k_count_deg<<<g1(E), blk256, 0, stream>>>(dstI, dinv, E);
  k_finish_dinv<<<g1(N), blk256, 0, stream>>>(dinv, N);

  // ---- layer 1a ----
  k_gemm<<<dim3(C_/64, N/64), gblk, 0, stream>>>(x, w1a, bufW, N, CIN_, C_);
  k_agg_init<<<g1(N*C_), blk256, 0, stream>>>(bufW, dinv, b1a, bufA, N*C_);
  k_agg_edges<<<dim3((unsigned)E), dim3(128), 0, stream>>>(srcI, dstI, dinv, bufW, bufA, E);
  hipMemsetAsync(gsum, 0, 2*(size_t)C_*sizeof(float), stream);
  k_bn_stats<<<dim3(256), blk256, 0, stream>>>(bufA, gsum, gsqs, N*C_);
  k_bn_apply<<<g1(N*C_), blk256, 0, stream>>>(bufA, nullptr, gsum, gsqs, g1a, be1a, bufA, N*C_, 1.0f/N);

  // ---- layer 1b (residual) ----
  k_gemm<<<dim3(C_/64, N/64), gblk, 0, stream>>>(bufA, w1b, bufW, N, C_, C_);
  k_agg_init<<<g1(N*C_), blk256, 0, stream>>>(bufW, dinv, b1b, bufB, N*C_);
  k_agg_edges<<<dim3((unsigned)E), dim3(128), 0, stream>>>(srcI, dstI, dinv, bufW, bufB, E);
  hipMemsetAsync(gsum, 0, 2*(size_t)C_*sizeof(float), stream);
  k_bn_stats<<<dim3(256), blk256, 0, stream>>>(bufB, gsum, gsqs, N*C_);
  k_bn_apply<<<g1(N*C_), blk256, 0, stream>>>(bufB, bufA, gsum, gsqs, g1b, be1b, bufB, N*C_, 1.0f/N);

  // ---- pool: s = softmax(gcn(hB, wp1, bp1)) ----
  k_gemm<<<dim3(K1_/64, N/64), gblk, 0, stream>>>(bufB, wp1, bufW, N, C_, K1_);
  k_agg_init<<<g1(N*K1_), blk256, 0, stream>>>(bufW, dinv, bp1, bufA, N*K1_);
  k_agg_edges<<<dim3((unsigned)E), dim3(128), 0, stream>>>(srcI, dstI, dinv, bufW, bufA, E);
  k_softmax128<<<dim3((unsigned)((N+3)/4)), blk256, 0, stream>>>(bufA, N);

  // t = A s (raw adjacency)
  hipMemsetAsync(bufW, 0, (size_t)N*C_*sizeof(float), stream);
  k_t_edges<<<dim3((unsigned)E), dim3(128), 0, stream>>>(srcI, dstI, bufA, bufW, E);

  // x2 = s^T h ; A2 = s^T t
  k_pool_gemm<<<dim3(C_/16, K1_/16, B_), gblk, 0, stream>>>(bufA, bufB, x2, NPG_);
  k_pool_gemm<<<dim3(K1_/16, K1_/16, B_), gblk, 0, stream>>>(bufA, bufW, A2, NPG_);

  // ---- dense stage ----
  k_dinv2<<<dim3((unsigned)M2), dim3(128), 0, stream>>>(A2, dinv2, M2);

  // layer 2a
  k_gemm<<<dim3(C_/64, M2/64), gblk, 0, stream>>>(x2, w2a, dW, M2, C_, C_);
  k_scale_rows<<<g1(M2*C_), blk256, 0, stream>>>(dW, dinv2, M2*C_);
  k_bgemm<<<dim3(C_/16, K1_/16, B_), gblk, 0, stream>>>(A2, dW, dT);
  k_dense_post<<<g1(M2*C_), blk256, 0, stream>>>(dT, dW, dinv2, b2a, M2*C_);
  hipMemsetAsync(gsum, 0, 2*(size_t)C_*sizeof(float), stream);
  k_bn_stats<<<dim3(64), blk256, 0, stream>>>(dT, gsum, gsqs, M2*C_);
  k_bn_apply<<<g1(M2*C_), blk256, 0, stream>>>(dT, nullptr, gsum, gsqs, g2a, be2a, h2a, M2*C_, 1.0f/M2);

  // layer 2b (residual)
  k_gemm<<<dim3(C_/64, M2/64), gblk, 0, stream>>>(h2a, w2b, dW, M2, C_, C_);
  k_scale_rows<<<g1(M2*C_), blk256, 0, stream>>>(dW, dinv2, M2*C_);
  k_bgemm<<<dim3(C_/16, K1_/16, B_), gblk, 0, stream>>>(A2, dW, dT);
  k_dense_post<<<g1(M2*C_), blk256, 0, stream>>>(dT, dW, dinv2, b2b, M2*C_);
  hipMemsetAsync(gsum, 0, 2*(size_t)C_*sizeof(float), stream);
  k_bn_stats<<<dim3(64), blk256, 0, stream>>>(dT, gsum, gsqs, M2*C_);
  k_bn_apply<<<g1(M2*C_), blk256, 0, stream>>>(dT, h2a, gsum, gsqs, g2b, be2b, h2b, M2*C_, 1.0f/M2);

  // ---- final: mean over pooled nodes (softmax rows sum to 1), linear, log_softmax ----
  int zero_idx = (out_size > B_*OUTc) ? B_*OUTc : -1;
  k_final<<<dim3((unsigned)B_), dim3(128), 0, stream>>>(h2b, wl, bl, out, K1_, C_, OUTc, 1.0f/K2_, zero_idx);
}

// Round 3
// 806.555 us; speedup vs baseline: 1.8206x; 1.8206x over previous
//
#include <hip/hip_runtime.h>
#include <cmath>

// ---------------- CSR build ----------------
__global__ void k_count_deg_i(const int* __restrict__ dst, int* __restrict__ deg, int E){
  int e = blockIdx.x*256 + threadIdx.x;
  if(e<E) atomicAdd(&deg[dst[e]], 1);
}

__global__ void k_make_dinv(const int* __restrict__ deg, float* __restrict__ dinv, int n){
  int i = blockIdx.x*256 + threadIdx.x;
  if(i<n) dinv[i] = rsqrtf((float)deg[i] + 1.0f);   // +1 self loop
}

// single-block exclusive scan of n=32768 ints (1024 threads x 32 each)
__global__ void k_scan(const int* __restrict__ deg, int* __restrict__ offs, int n){
  __shared__ int bs[1024];
  int t = threadIdx.x;
  int per = n >> 10;                 // 32
  int base = t*per;
  int loc[32];
  int s = 0;
  for(int i=0;i<per;i++){ loc[i] = s; s += deg[base+i]; }
  bs[t] = s;
  __syncthreads();
  for(int o=1;o<1024;o<<=1){
    int v = (t>=o) ? bs[t-o] : 0;
    __syncthreads();
    bs[t] += v;
    __syncthreads();
  }
  int tb = (t==0) ? 0 : bs[t-1];
  for(int i=0;i<per;i++) offs[base+i] = tb + loc[i];
  if(t==1023) offs[n] = tb + s;
}

__global__ void k_fill(const int* __restrict__ src, const int* __restrict__ dst,
                       int* __restrict__ cursor, const int* __restrict__ offs,
                       int* __restrict__ esrc, int E){
  int e = blockIdx.x*256 + threadIdx.x;
  if(e<E){
    int d = dst[e];
    int p = atomicAdd(&cursor[d], 1);
    esrc[offs[d]+p] = src[e];
  }
}

// ---------------- GEMM: C(fp32[M,Nc]) = A[M,K] @ B[K,Nc], optional row scale ----------------
// M%64==0, Nc%64==0, K%16==0. block 16x16, 64x64 tile, 4x4 per thread.
__global__ void k_gemm(const float* __restrict__ A, const float* __restrict__ B,
                       float* __restrict__ C, int M, int K, int Nc,
                       const float* __restrict__ rowscale){
  __shared__ float As[16][65];
  __shared__ float Bs[16][65];
  const int tx = threadIdx.x, ty = threadIdx.y;
  const int tid = ty*16 + tx;
  const int row0 = blockIdx.y*64, col0 = blockIdx.x*64;
  float acc[4][4] = {};
  for(int kt=0; kt<K; kt+=16){
    #pragma unroll
    for(int i=0;i<4;i++){
      int idx = i*256 + tid;
      As[idx & 15][idx >> 4] = A[(size_t)(row0 + (idx>>4))*K + kt + (idx&15)];
    }
    #pragma unroll
    for(int i=0;i<4;i++){
      int idx = i*256 + tid;
      Bs[idx >> 6][idx & 63] = B[(size_t)(kt + (idx>>6))*Nc + col0 + (idx&63)];
    }
    __syncthreads();
    #pragma unroll
    for(int k=0;k<16;k++){
      float a[4], b[4];
      #pragma unroll
      for(int i=0;i<4;i++) a[i] = As[k][ty*4+i];
      #pragma unroll
      for(int j=0;j<4;j++) b[j] = Bs[k][tx*4+j];
      #pragma unroll
      for(int i=0;i<4;i++)
        #pragma unroll
        for(int j=0;j<4;j++) acc[i][j] += a[i]*b[j];
    }
    __syncthreads();
  }
  #pragma unroll
  for(int i=0;i<4;i++){
    int r = row0 + ty*4 + i;
    float sc = rowscale ? rowscale[r] : 1.0f;
    #pragma unroll
    for(int j=0;j<4;j++)
      C[(size_t)r*Nc + col0 + tx*4 + j] = acc[i][j]*sc;
  }
}

// ---------------- CSR-gather GCN aggregate (C == 128) ----------------
// input hWs already row-scaled by dinv. one block (128 threads) per dst node.
// out[d,c] = dinv[d]*(sum_{s in N(d)} hWs[s,c] + hWs[d,c]) + bias[c]
template<bool DO_SOFTMAX>
__global__ void k_gather_gcn(const int* __restrict__ offs, const int* __restrict__ esrc,
                             const float* __restrict__ dinv, const float* __restrict__ hWs,
                             const float* __restrict__ bias, float* __restrict__ out){
  __shared__ float red[2], red2[2];
  int d = blockIdx.x;
  int c = threadIdx.x;                    // 128
  int beg = offs[d], end = offs[d+1];
  float acc = hWs[(size_t)d*128 + c];     // self loop
  for(int j=beg; j<end; j++){
    int s = esrc[j];                      // uniform across block -> broadcast
    acc += hWs[(size_t)s*128 + c];
  }
  float v = dinv[d]*acc + bias[c];
  if(DO_SOFTMAX){
    float m = v;
    #pragma unroll
    for(int o=32;o>0;o>>=1) m = fmaxf(m, __shfl_xor(m,o));
    if((c&63)==0) red[c>>6] = m;
    __syncthreads();
    m = fmaxf(red[0], red[1]);
    float e = __expf(v-m);
    float ssum = e;
    #pragma unroll
    for(int o=32;o>0;o>>=1) ssum += __shfl_xor(ssum,o);
    if((c&63)==0) red2[c>>6] = ssum;
    __syncthreads();
    v = e/(red2[0]+red2[1]);
  }
  out[(size_t)d*128 + c] = v;
}

// t[d,c] = sum_{s in N(d)} sM[s,c]   (raw adjacency @ s)
__global__ void k_gather_sum(const int* __restrict__ offs, const int* __restrict__ esrc,
                             const float* __restrict__ sM, float* __restrict__ out){
  int d = blockIdx.x;
  int c = threadIdx.x;
  int beg = offs[d], end = offs[d+1];
  float acc = 0.f;
  for(int j=beg; j<end; j++)
    acc += sM[(size_t)esrc[j]*128 + c];
  out[(size_t)d*128 + c] = acc;
}

// ---------------- BatchNorm (C == 128) ----------------
__global__ void k_bn_stats(const float* __restrict__ x, float* __restrict__ gsum,
                           float* __restrict__ gsqs, int n){
  __shared__ float ss[256], sq[256];
  int t = threadIdx.x;
  float s0 = 0.f, q0 = 0.f;
  for(int i = blockIdx.x*256 + t; i < n; i += gridDim.x*256){
    float v = x[i];
    s0 += v; q0 += v*v;
  }
  ss[t] = s0; sq[t] = q0;
  __syncthreads();
  if(t < 128){
    atomicAdd(&gsum[t], ss[t] + ss[t+128]);
    atomicAdd(&gsqs[t], sq[t] + sq[t+128]);
  }
}

__global__ void k_bn_apply(const float* __restrict__ x, const float* __restrict__ res,
                           const float* __restrict__ gsum, const float* __restrict__ gsqs,
                           const float* __restrict__ gamma, const float* __restrict__ beta,
                           float* __restrict__ out, int n, float invM){
  int i = blockIdx.x*256 + threadIdx.x;
  if(i<n){
    int c = i & 127;
    float m = gsum[c]*invM;
    float v = gsqs[c]*invM - m*m;
    float xh = (x[i]-m)*rsqrtf(v + 1e-5f);
    float y = gamma[c]*xh + beta[c];
    y = y / (1.f + __expf(-y));
    out[i] = (res ? res[i] : 0.f) + y;
  }
}

// ---------------- pooled gemm: out[b,i,j] = sum_n P[b,n,i]*Q[b,n,j] ----------------
__global__ void k_pool_gemm(const float* __restrict__ P, const float* __restrict__ Q,
                            float* __restrict__ out, int npg){
  __shared__ float Ps[16][17], Qs[16][17];
  int b = blockIdx.z;
  int i0 = blockIdx.y*16, j0 = blockIdx.x*16;
  int tx = threadIdx.x, ty = threadIdx.y;
  const float* Pb = P + (size_t)b*npg*128;
  const float* Qb = Q + (size_t)b*npg*128;
  float acc = 0.f;
  for(int n0=0; n0<npg; n0+=16){
    Ps[ty][tx] = Pb[(size_t)(n0+ty)*128 + i0 + tx];
    Qs[ty][tx] = Qb[(size_t)(n0+ty)*128 + j0 + tx];
    __syncthreads();
    #pragma unroll
    for(int k=0;k<16;k++) acc += Ps[k][ty]*Qs[k][tx];
    __syncthreads();
  }
  out[((size_t)b*128 + i0+ty)*128 + j0+tx] = acc;
}

// ---------------- dense stage ----------------
__global__ void k_dinv2(const float* __restrict__ A2, float* __restrict__ dinv2, int rows){
  int r = blockIdx.x;
  int t = threadIdx.x;               // 128
  float v = A2[(size_t)r*128 + t];
  #pragma unroll
  for(int o=32;o>0;o>>=1) v += __shfl_xor(v, o);
  __shared__ float w[2];
  if((t & 63) == 0) w[t>>6] = v;
  __syncthreads();
  if(t==0) dinv2[r] = rsqrtf(w[0] + w[1] + 1.0f);
}

// out[b] = A2[b](128x128) @ X[b](128x128)
__global__ void k_bgemm(const float* __restrict__ A, const float* __restrict__ X,
                        float* __restrict__ out){
  __shared__ float As[16][17], Xs[16][17];
  int b = blockIdx.z;
  int i0 = blockIdx.y*16, j0 = blockIdx.x*16;
  int tx = threadIdx.x, ty = threadIdx.y;
  const float* Ab = A + (size_t)b*128*128;
  const float* Xb = X + (size_t)b*128*128;
  float acc = 0.f;
  for(int k0=0;k0<128;k0+=16){
    As[ty][tx] = Ab[(i0+ty)*128 + k0+tx];
    Xs[ty][tx] = Xb[(k0+ty)*128 + j0+tx];
    __syncthreads();
    #pragma unroll
    for(int k=0;k<16;k++) acc += As[ty][k]*Xs[k][tx];
    __syncthreads();
  }
  out[((size_t)b*128 + i0+ty)*128 + j0+tx] = acc;
}

// tmp = dinv2[r]*(tmp + hws) + bias[c]
__global__ void k_dense_post(float* __restrict__ tmp, const float* __restrict__ hws,
                             const float* __restrict__ dinv2, const float* __restrict__ bias,
                             int n){
  int i = blockIdx.x*256 + threadIdx.x;
  if(i<n)
    tmp[i] = dinv2[i>>7]*(tmp[i] + hws[i]) + bias[i & 127];
}

// ---------------- final ----------------
__global__ void k_final(const float* __restrict__ h2, const float* __restrict__ wl,
                        const float* __restrict__ bl, float* __restrict__ out,
                        int K1n, int Cc, int OUTc, float inv_k2, int zero_idx){
  int b = blockIdx.x;
  int t = threadIdx.x;                // 128
  __shared__ float g[128];
  __shared__ float logits[32];
  __shared__ float mred, lred;
  const float* hb = h2 + (size_t)b*K1n*Cc;
  float acc = 0.f;
  for(int n=0;n<K1n;n++) acc += hb[(size_t)n*Cc + t];
  g[t] = acc * inv_k2;
  __syncthreads();
  if(t < OUTc){
    float l = bl[t];
    for(int d=0; d<Cc; d++) l += g[d]*wl[d*OUTc + t];
    logits[t] = l;
  }
  __syncthreads();
  if(t==0){
    float m = -1e30f;
    for(int o=0;o<OUTc;o++) m = fmaxf(m, logits[o]);
    float s = 0.f;
    for(int o=0;o<OUTc;o++) s += __expf(logits[o]-m);
    mred = m; lred = logf(s);
  }
  __syncthreads();
  if(t < OUTc) out[b*OUTc + t] = logits[t] - mred - lred;
  if(b==0 && t==0 && zero_idx >= 0) out[zero_idx] = 0.f;
}

// ---------------- launch ----------------
extern "C" void kernel_launch(void* const* d_in, const int* in_sizes, int n_in,
                              void* d_out, int out_size, void* d_ws, size_t ws_size,
                              hipStream_t stream){
  const float* x    = (const float*)d_in[0];
  const int*   ei   = (const int*)d_in[1];
  const float* w1a  = (const float*)d_in[4];
  const float* b1a  = (const float*)d_in[5];
  const float* g1a  = (const float*)d_in[6];
  const float* be1a = (const float*)d_in[7];
  const float* w1b  = (const float*)d_in[8];
  const float* b1b  = (const float*)d_in[9];
  const float* g1b  = (const float*)d_in[10];
  const float* be1b = (const float*)d_in[11];
  const float* wp1  = (const float*)d_in[12];
  const float* bp1  = (const float*)d_in[13];
  const float* w2a  = (const float*)d_in[14];
  const float* b2a  = (const float*)d_in[15];
  const float* g2a  = (const float*)d_in[16];
  const float* be2a = (const float*)d_in[17];
  const float* w2b  = (const float*)d_in[18];
  const float* b2b  = (const float*)d_in[19];
  const float* g2b  = (const float*)d_in[20];
  const float* be2b = (const float*)d_in[21];
  const float* wl   = (const float*)d_in[24];
  const float* bl   = (const float*)d_in[25];
  float* out = (float*)d_out;

  const int C_   = in_sizes[5];            // 128
  const int CIN_ = in_sizes[4]/C_;         // 64
  const int N    = in_sizes[0]/CIN_;       // 32768
  const int E    = in_sizes[1]/2;          // 524288
  const int B_   = in_sizes[3]-1;          // 32
  const int NPG_ = N/B_;                   // 1024
  const int K1_  = in_sizes[13];           // 128
  const int K2_  = in_sizes[23];           // 32
  const int OUTc = in_sizes[25];           // 10
  const int M2   = B_*K1_;                 // 4096

  const int* srcI = ei;
  const int* dstI = ei + E;

  float* ws = (float*)d_ws;
  size_t o = 0;
  float* dinv  = ws + o; o += (size_t)N;
  float* bufW  = ws + o; o += (size_t)N*C_;
  float* bufA  = ws + o; o += (size_t)N*C_;
  float* bufB  = ws + o; o += (size_t)N*C_;
  float* x2    = ws + o; o += (size_t)M2*C_;
  float* A2    = ws + o; o += (size_t)M2*K1_;
  float* dinv2 = ws + o; o += (size_t)M2;
  float* dW    = ws + o; o += (size_t)M2*C_;
  float* dT    = ws + o; o += (size_t)M2*C_;
  float* h2a   = ws + o; o += (size_t)M2*C_;
  float* h2b   = ws + o; o += (size_t)M2*C_;
  float* gsum  = ws + o; o += (size_t)C_;
  float* gsqs  = ws + o; o += (size_t)C_;
  int* degi    = (int*)(ws + o); o += (size_t)N;
  int* offs    = (int*)(ws + o); o += (size_t)N + 1;
  int* cursor  = (int*)(ws + o); o += (size_t)N;
  int* esrc    = (int*)(ws + o); o += (size_t)E;
  (void)ws_size; (void)n_in;

  dim3 blk256(256);
  dim3 gblk(16,16);
  auto g1 = [](int n){ return dim3((unsigned)((n+255)/256)); };

  // ---- CSR build (once; reused by all 4 aggregations) ----
  hipMemsetAsync(degi, 0, (size_t)N*sizeof(int), stream);
  hipMemsetAsync(cursor, 0, (size_t)N*sizeof(int), stream);
  k_count_deg_i<<<g1(E), blk256, 0, stream>>>(dstI, degi, E);
  k_make_dinv<<<g1(N), blk256, 0, stream>>>(degi, dinv, N);
  k_scan<<<dim3(1), dim3(1024), 0, stream>>>(degi, offs, N);
  k_fill<<<g1(E), blk256, 0, stream>>>(srcI, dstI, cursor, offs, esrc, E);

  // ---- layer 1a ----
  k_gemm<<<dim3(C_/64, N/64), gblk, 0, stream>>>(x, w1a, bufW, N, CIN_, C_, dinv);
  k_gather_gcn<false><<<dim3((unsigned)N), dim3(128), 0, stream>>>(offs, esrc, dinv, bufW, b1a, bufA);
  hipMemsetAsync(gsum, 0, 2*(size_t)C_*sizeof(float), stream);
  k_bn_stats<<<dim3(256), blk256, 0, stream>>>(bufA, gsum, gsqs, N*C_);
  k_bn_apply<<<g1(N*C_), blk256, 0, stream>>>(bufA, nullptr, gsum, gsqs, g1a, be1a, bufA, N*C_, 1.0f/N);

  // ---- layer 1b (residual) ----
  k_gemm<<<dim3(C_/64, N/64), gblk, 0, stream>>>(bufA, w1b, bufW, N, C_, C_, dinv);
  k_gather_gcn<false><<<dim3((unsigned)N), dim3(128), 0, stream>>>(offs, esrc, dinv, bufW, b1b, bufB);
  hipMemsetAsync(gsum, 0, 2*(size_t)C_*sizeof(float), stream);
  k_bn_stats<<<dim3(256), blk256, 0, stream>>>(bufB, gsum, gsqs, N*C_);
  k_bn_apply<<<g1(N*C_), blk256, 0, stream>>>(bufB, bufA, gsum, gsqs, g1b, be1b, bufB, N*C_, 1.0f/N);

  // ---- pool: s = softmax(gcn(hB, wp1, bp1)) (softmax fused into gather) ----
  k_gemm<<<dim3(K1_/64, N/64), gblk, 0, stream>>>(bufB, wp1, bufW, N, C_, K1_, dinv);
  k_gather_gcn<true><<<dim3((unsigned)N), dim3(128), 0, stream>>>(offs, esrc, dinv, bufW, bp1, bufA);

  // t = A s (raw adjacency)
  k_gather_sum<<<dim3((unsigned)N), dim3(128), 0, stream>>>(offs, esrc, bufA, bufW);

  // x2 = s^T h ; A2 = s^T t
  k_pool_gemm<<<dim3(C_/16, K1_/16, B_), gblk, 0, stream>>>(bufA, bufB, x2, NPG_);
  k_pool_gemm<<<dim3(K1_/16, K1_/16, B_), gblk, 0, stream>>>(bufA, bufW, A2, NPG_);

  // ---- dense stage ----
  k_dinv2<<<dim3((unsigned)M2), dim3(128), 0, stream>>>(A2, dinv2, M2);

  // layer 2a
  k_gemm<<<dim3(C_/64, M2/64), gblk, 0, stream>>>(x2, w2a, dW, M2, C_, C_, dinv2);
  k_bgemm<<<dim3(C_/16, K1_/16, B_), gblk, 0, stream>>>(A2, dW, dT);
  k_dense_post<<<g1(M2*C_), blk256, 0, stream>>>(dT, dW, dinv2, b2a, M2*C_);
  hipMemsetAsync(gsum, 0, 2*(size_t)C_*sizeof(float), stream);
  k_bn_stats<<<dim3(64), blk256, 0, stream>>>(dT, gsum, gsqs, M2*C_);
  k_bn_apply<<<g1(M2*C_), blk256, 0, stream>>>(dT, nullptr, gsum, gsqs, g2a, be2a, h2a, M2*C_, 1.0f/M2);

  // layer 2b (residual)
  k_gemm<<<dim3(C_/64, M2/64), gblk, 0, stream>>>(h2a, w2b, dW, M2, C_, C_, dinv2);
  k_bgemm<<<dim3(C_/16, K1_/16, B_), gblk, 0, stream>>>(A2, dW, dT);
  k_dense_post<<<g1(M2*C_), blk256, 0, stream>>>(dT, dW, dinv2, b2b, M2*C_);
  hipMemsetAsync(gsum, 0, 2*(size_t)C_*sizeof(float), stream);
  k_bn_stats<<<dim3(64), blk256, 0, stream>>>(dT, gsum, gsqs, M2*C_);
  k_bn_apply<<<g1(M2*C_), blk256, 0, stream>>>(dT, h2a, gsum, gsqs, g2b, be2b, h2b, M2*C_, 1.0f/M2);

  // ---- final ----
  int zero_idx = (out_size > B_*OUTc) ? B_*OUTc : -1;
  k_final<<<dim3((unsigned)B_), dim3(128), 0, stream>>>(h2b, wl, bl, out, K1_, C_, OUTc, 1.0f/K2_, zero_idx);
}

// Round 4
// 607.428 us; speedup vs baseline: 2.4175x; 1.3278x over previous
//
#include <hip/hip_runtime.h>
#include <cmath>

#define KSPLIT 16

// ---------------- CSR build ----------------
__global__ void k_count_deg_i(const int* __restrict__ dst, int* __restrict__ deg, int E){
  int e = blockIdx.x*256 + threadIdx.x;
  if(e<E) atomicAdd(&deg[dst[e]], 1);
}

__global__ void k_make_dinv(const int* __restrict__ deg, float* __restrict__ dinv, int n){
  int i = blockIdx.x*256 + threadIdx.x;
  if(i<n) dinv[i] = rsqrtf((float)deg[i] + 1.0f);   // +1 self loop
}

// single-block exclusive scan of n=32768 ints (1024 threads x 32 each)
__global__ void k_scan(const int* __restrict__ deg, int* __restrict__ offs, int n){
  __shared__ int bs[1024];
  int t = threadIdx.x;
  int per = n >> 10;                 // 32
  int base = t*per;
  int loc[32];
  int s = 0;
  for(int i=0;i<per;i++){ loc[i] = s; s += deg[base+i]; }
  bs[t] = s;
  __syncthreads();
  for(int o=1;o<1024;o<<=1){
    int v = (t>=o) ? bs[t-o] : 0;
    __syncthreads();
    bs[t] += v;
    __syncthreads();
  }
  int tb = (t==0) ? 0 : bs[t-1];
  for(int i=0;i<per;i++) offs[base+i] = tb + loc[i];
  if(t==1023) offs[n] = tb + s;
}

__global__ void k_fill(const int* __restrict__ src, const int* __restrict__ dst,
                       int* __restrict__ cursor, const int* __restrict__ offs,
                       int* __restrict__ esrc, int E){
  int e = blockIdx.x*256 + threadIdx.x;
  if(e<E){
    int d = dst[e];
    int p = atomicAdd(&cursor[d], 1);
    esrc[offs[d]+p] = src[e];
  }
}

// ---------------- GEMM 64x64 tile (small M) ----------------
__global__ void k_gemm(const float* __restrict__ A, const float* __restrict__ B,
                       float* __restrict__ C, int M, int K, int Nc,
                       const float* __restrict__ rowscale){
  __shared__ float As[16][65];
  __shared__ float Bs[16][65];
  const int tx = threadIdx.x, ty = threadIdx.y;
  const int tid = ty*16 + tx;
  const int row0 = blockIdx.y*64, col0 = blockIdx.x*64;
  float acc[4][4] = {};
  for(int kt=0; kt<K; kt+=16){
    #pragma unroll
    for(int i=0;i<4;i++){
      int idx = i*256 + tid;
      As[idx & 15][idx >> 4] = A[(size_t)(row0 + (idx>>4))*K + kt + (idx&15)];
    }
    #pragma unroll
    for(int i=0;i<4;i++){
      int idx = i*256 + tid;
      Bs[idx >> 6][idx & 63] = B[(size_t)(kt + (idx>>6))*Nc + col0 + (idx&63)];
    }
    __syncthreads();
    #pragma unroll
    for(int k=0;k<16;k++){
      float a[4], b[4];
      #pragma unroll
      for(int i=0;i<4;i++) a[i] = As[k][ty*4+i];
      #pragma unroll
      for(int j=0;j<4;j++) b[j] = Bs[k][tx*4+j];
      #pragma unroll
      for(int i=0;i<4;i++)
        #pragma unroll
        for(int j=0;j<4;j++) acc[i][j] += a[i]*b[j];
    }
    __syncthreads();
  }
  #pragma unroll
  for(int i=0;i<4;i++){
    int r = row0 + ty*4 + i;
    float sc = rowscale ? rowscale[r] : 1.0f;
    #pragma unroll
    for(int j=0;j<4;j++)
      C[(size_t)r*Nc + col0 + tx*4 + j] = acc[i][j]*sc;
  }
}

// ---------------- GEMM 128x128 tile, 8x8 per thread (big M; Nc%128==0, K%16==0) ----------------
__global__ void k_gemm2(const float* __restrict__ A, const float* __restrict__ B,
                        float* __restrict__ C, int M, int K, int Nc,
                        const float* __restrict__ rowscale){
  __shared__ float As[16][129];
  __shared__ float Bs[16][132];
  int tid = threadIdx.x;
  int tx = tid & 15, ty = tid >> 4;
  int row0 = blockIdx.y*128, col0 = blockIdx.x*128;
  float acc[8][8] = {};
  for(int kc=0; kc<K; kc+=16){
    int r = tid >> 1, c8 = (tid & 1)*8;
    float4 v0 = *(const float4*)&A[(size_t)(row0+r)*K + kc + c8];
    float4 v1 = *(const float4*)&A[(size_t)(row0+r)*K + kc + c8 + 4];
    As[c8+0][r]=v0.x; As[c8+1][r]=v0.y; As[c8+2][r]=v0.z; As[c8+3][r]=v0.w;
    As[c8+4][r]=v1.x; As[c8+5][r]=v1.y; As[c8+6][r]=v1.z; As[c8+7][r]=v1.w;
    int r2 = tid >> 4, j8 = (tid & 15)*8;
    *(float4*)&Bs[r2][j8]   = *(const float4*)&B[(size_t)(kc+r2)*Nc + col0 + j8];
    *(float4*)&Bs[r2][j8+4] = *(const float4*)&B[(size_t)(kc+r2)*Nc + col0 + j8 + 4];
    __syncthreads();
    #pragma unroll
    for(int k=0;k<16;k++){
      float4 a0 = *(const float4*)&As[k][ty*4];
      float4 a1 = *(const float4*)&As[k][64+ty*4];
      float4 b0 = *(const float4*)&Bs[k][tx*4];
      float4 b1 = *(const float4*)&Bs[k][64+tx*4];
      float av[8]={a0.x,a0.y,a0.z,a0.w,a1.x,a1.y,a1.z,a1.w};
      float bv[8]={b0.x,b0.y,b0.z,b0.w,b1.x,b1.y,b1.z,b1.w};
      #pragma unroll
      for(int i=0;i<8;i++)
        #pragma unroll
        for(int j=0;j<8;j++) acc[i][j] += av[i]*bv[j];
    }
    __syncthreads();
  }
  #pragma unroll
  for(int ih=0; ih<2; ih++)
    #pragma unroll
    for(int ii=0; ii<4; ii++){
      int i = row0 + ih*64 + ty*4 + ii;
      float sc = rowscale ? rowscale[i] : 1.0f;
      #pragma unroll
      for(int jh=0; jh<2; jh++){
        float4 v;
        v.x = acc[ih*4+ii][jh*4+0]*sc;
        v.y = acc[ih*4+ii][jh*4+1]*sc;
        v.z = acc[ih*4+ii][jh*4+2]*sc;
        v.w = acc[ih*4+ii][jh*4+3]*sc;
        *(float4*)&C[(size_t)i*Nc + col0 + jh*64 + tx*4] = v;
      }
    }
}

// ---------------- CSR-gather GCN aggregate (C == 128), XCD-swizzled ----------------
template<bool DO_SOFTMAX>
__global__ void k_gather_gcn(const int* __restrict__ offs, const int* __restrict__ esrc,
                             const float* __restrict__ dinv, const float* __restrict__ hWs,
                             const float* __restrict__ bias, float* __restrict__ out){
  __shared__ float red[2], red2[2];
  int bid = blockIdx.x;
  int d = ((bid & 7) << 12) | (bid >> 3);   // XCD-local graph grouping
  int c = threadIdx.x;                      // 128
  int beg = offs[d], end = offs[d+1];
  float acc0 = hWs[(size_t)d*128 + c];      // self loop
  float acc1 = 0.f;
  int j = beg;
  for(; j+1<end; j+=2){
    int s0 = esrc[j], s1 = esrc[j+1];
    acc0 += hWs[(size_t)s0*128 + c];
    acc1 += hWs[(size_t)s1*128 + c];
  }
  if(j<end) acc1 += hWs[(size_t)esrc[j]*128 + c];
  float v = dinv[d]*(acc0+acc1) + bias[c];
  if(DO_SOFTMAX){
    float m = v;
    #pragma unroll
    for(int o=32;o>0;o>>=1) m = fmaxf(m, __shfl_xor(m,o));
    if((c&63)==0) red[c>>6] = m;
    __syncthreads();
    m = fmaxf(red[0], red[1]);
    float e = __expf(v-m);
    float ssum = e;
    #pragma unroll
    for(int o=32;o>0;o>>=1) ssum += __shfl_xor(ssum,o);
    if((c&63)==0) red2[c>>6] = ssum;
    __syncthreads();
    v = e/(red2[0]+red2[1]);
  }
  out[(size_t)d*128 + c] = v;
}

__global__ void k_gather_sum(const int* __restrict__ offs, const int* __restrict__ esrc,
                             const float* __restrict__ sM, float* __restrict__ out){
  int bid = blockIdx.x;
  int d = ((bid & 7) << 12) | (bid >> 3);
  int c = threadIdx.x;
  int beg = offs[d], end = offs[d+1];
  float acc0 = 0.f, acc1 = 0.f;
  int j = beg;
  for(; j+1<end; j+=2){
    int s0 = esrc[j], s1 = esrc[j+1];
    acc0 += sM[(size_t)s0*128 + c];
    acc1 += sM[(size_t)s1*128 + c];
  }
  if(j<end) acc1 += sM[(size_t)esrc[j]*128 + c];
  out[(size_t)d*128 + c] = acc0 + acc1;
}

// ---------------- BatchNorm (C == 128) ----------------
__global__ void k_bn_stats(const float* __restrict__ x, float* __restrict__ gsum,
                           float* __restrict__ gsqs, int n){
  __shared__ float ss[256], sq[256];
  int t = threadIdx.x;
  float s0 = 0.f, q0 = 0.f;
  for(int i = blockIdx.x*256 + t; i < n; i += gridDim.x*256){
    float v = x[i];
    s0 += v; q0 += v*v;
  }
  ss[t] = s0; sq[t] = q0;
  __syncthreads();
  if(t < 128){
    atomicAdd(&gsum[t], ss[t] + ss[t+128]);
    atomicAdd(&gsqs[t], sq[t] + sq[t+128]);
  }
}

__global__ void k_bn_apply(const float* __restrict__ x, const float* __restrict__ res,
                           const float* __restrict__ gsum, const float* __restrict__ gsqs,
                           const float* __restrict__ gamma, const float* __restrict__ beta,
                           float* __restrict__ out, int n, float invM){
  int i = blockIdx.x*256 + threadIdx.x;
  if(i<n){
    int c = i & 127;
    float m = gsum[c]*invM;
    float v = gsqs[c]*invM - m*m;
    float xh = (x[i]-m)*rsqrtf(v + 1e-5f);
    float y = gamma[c]*xh + beta[c];
    y = y / (1.f + __expf(-y));
    out[i] = (res ? res[i] : 0.f) + y;
  }
}

// ---------------- pool: part[ks,b,i,j] = sum_{n in chunk ks} P[b,n,i]*Q[b,n,j] ----------------
__global__ void k_pool_split(const float* __restrict__ P, const float* __restrict__ Q,
                             float* __restrict__ part, int npg){
  __shared__ float Ps[8][132], Qs[8][132];
  int ks = blockIdx.x, b = blockIdx.y;
  int klen = npg / KSPLIT;
  const float* Pb = P + ((size_t)b*npg + (size_t)ks*klen)*128;
  const float* Qb = Q + ((size_t)b*npg + (size_t)ks*klen)*128;
  int tid = threadIdx.x;
  int tx = tid & 15, ty = tid >> 4;
  float acc[8][8] = {};
  for(int n0=0; n0<klen; n0+=8){
    int r = tid >> 5, c4 = (tid & 31)*4;
    *(float4*)&Ps[r][c4] = *(const float4*)&Pb[(size_t)(n0+r)*128 + c4];
    *(float4*)&Qs[r][c4] = *(const float4*)&Qb[(size_t)(n0+r)*128 + c4];
    __syncthreads();
    #pragma unroll
    for(int k=0;k<8;k++){
      float4 a0 = *(const float4*)&Ps[k][ty*4];
      float4 a1 = *(const float4*)&Ps[k][64+ty*4];
      float4 b0 = *(const float4*)&Qs[k][tx*4];
      float4 b1 = *(const float4*)&Qs[k][64+tx*4];
      float av[8]={a0.x,a0.y,a0.z,a0.w,a1.x,a1.y,a1.z,a1.w};
      float bv[8]={b0.x,b0.y,b0.z,b0.w,b1.x,b1.y,b1.z,b1.w};
      #pragma unroll
      for(int i=0;i<8;i++)
        #pragma unroll
        for(int j=0;j<8;j++) acc[i][j] += av[i]*bv[j];
    }
    __syncthreads();
  }
  float* outp = part + ((size_t)(ks*gridDim.y + b)*128)*128;
  #pragma unroll
  for(int ih=0; ih<2; ih++)
    #pragma unroll
    for(int ii=0; ii<4; ii++){
      int i = ih*64 + ty*4 + ii;
      #pragma unroll
      for(int jh=0; jh<2; jh++){
        float4 v;
        v.x = acc[ih*4+ii][jh*4+0];
        v.y = acc[ih*4+ii][jh*4+1];
        v.z = acc[ih*4+ii][jh*4+2];
        v.w = acc[ih*4+ii][jh*4+3];
        *(float4*)&outp[(size_t)i*128 + jh*64 + tx*4] = v;
      }
    }
}

__global__ void k_pool_reduce(const float* __restrict__ part, float* __restrict__ out, int total){
  int i = blockIdx.x*256 + threadIdx.x;
  if(i*4 < total){
    float4 s = *(const float4*)&part[(size_t)i*4];
    #pragma unroll
    for(int ks=1; ks<KSPLIT; ks++){
      float4 v = *(const float4*)&part[(size_t)ks*total + (size_t)i*4];
      s.x+=v.x; s.y+=v.y; s.z+=v.z; s.w+=v.w;
    }
    *(float4*)&out[(size_t)i*4] = s;
  }
}

// ---------------- dense stage ----------------
__global__ void k_dinv2(const float* __restrict__ A2, float* __restrict__ dinv2, int rows){
  int r = blockIdx.x;
  int t = threadIdx.x;               // 128
  float v = A2[(size_t)r*128 + t];
  #pragma unroll
  for(int o=32;o>0;o>>=1) v += __shfl_xor(v, o);
  __shared__ float w[2];
  if((t & 63) == 0) w[t>>6] = v;
  __syncthreads();
  if(t==0) dinv2[r] = rsqrtf(w[0] + w[1] + 1.0f);
}

__global__ void k_bgemm(const float* __restrict__ A, const float* __restrict__ X,
                        float* __restrict__ out){
  __shared__ float As[16][17], Xs[16][17];
  int b = blockIdx.z;
  int i0 = blockIdx.y*16, j0 = blockIdx.x*16;
  int tx = threadIdx.x, ty = threadIdx.y;
  const float* Ab = A + (size_t)b*128*128;
  const float* Xb = X + (size_t)b*128*128;
  float acc = 0.f;
  for(int k0=0;k0<128;k0+=16){
    As[ty][tx] = Ab[(i0+ty)*128 + k0+tx];
    Xs[ty][tx] = Xb[(k0+ty)*128 + j0+tx];
    __syncthreads();
    #pragma unroll
    for(int k=0;k<16;k++) acc += As[ty][k]*Xs[k][tx];
    __syncthreads();
  }
  out[((size_t)b*128 + i0+ty)*128 + j0+tx] = acc;
}

__global__ void k_dense_post(float* __restrict__ tmp, const float* __restrict__ hws,
                             const float* __restrict__ dinv2, const float* __restrict__ bias,
                             int n){
  int i = blockIdx.x*256 + threadIdx.x;
  if(i<n)
    tmp[i] = dinv2[i>>7]*(tmp[i] + hws[i]) + bias[i & 127];
}

// ---------------- final ----------------
__global__ void k_final(const float* __restrict__ h2, const float* __restrict__ wl,
                        const float* __restrict__ bl, float* __restrict__ out,
                        int K1n, int Cc, int OUTc, float inv_k2, int zero_idx){
  int b = blockIdx.x;
  int t = threadIdx.x;                // 128
  __shared__ float g[128];
  __shared__ float logits[32];
  __shared__ float mred, lred;
  const float* hb = h2 + (size_t)b*K1n*Cc;
  float acc = 0.f;
  for(int n=0;n<K1n;n++) acc += hb[(size_t)n*Cc + t];
  g[t] = acc * inv_k2;
  __syncthreads();
  if(t < OUTc){
    float l = bl[t];
    for(int d=0; d<Cc; d++) l += g[d]*wl[d*OUTc + t];
    logits[t] = l;
  }
  __syncthreads();
  if(t==0){
    float m = -1e30f;
    for(int o=0;o<OUTc;o++) m = fmaxf(m, logits[o]);
    float s = 0.f;
    for(int o=0;o<OUTc;o++) s += __expf(logits[o]-m);
    mred = m; lred = logf(s);
  }
  __syncthreads();
  if(t < OUTc) out[b*OUTc + t] = logits[t] - mred - lred;
  if(b==0 && t==0 && zero_idx >= 0) out[zero_idx] = 0.f;
}

// ---------------- launch ----------------
extern "C" void kernel_launch(void* const* d_in, const int* in_sizes, int n_in,
                              void* d_out, int out_size, void* d_ws, size_t ws_size,
                              hipStream_t stream){
  const float* x    = (const float*)d_in[0];
  const int*   ei   = (const int*)d_in[1];
  const float* w1a  = (const float*)d_in[4];
  const float* b1a  = (const float*)d_in[5];
  const float* g1a  = (const float*)d_in[6];
  const float* be1a = (const float*)d_in[7];
  const float* w1b  = (const float*)d_in[8];
  const float* b1b  = (const float*)d_in[9];
  const float* g1b  = (const float*)d_in[10];
  const float* be1b = (const float*)d_in[11];
  const float* wp1  = (const float*)d_in[12];
  const float* bp1  = (const float*)d_in[13];
  const float* w2a  = (const float*)d_in[14];
  const float* b2a  = (const float*)d_in[15];
  const float* g2a  = (const float*)d_in[16];
  const float* be2a = (const float*)d_in[17];
  const float* w2b  = (const float*)d_in[18];
  const float* b2b  = (const float*)d_in[19];
  const float* g2b  = (const float*)d_in[20];
  const float* be2b = (const float*)d_in[21];
  const float* wl   = (const float*)d_in[24];
  const float* bl   = (const float*)d_in[25];
  float* out = (float*)d_out;

  const int C_   = in_sizes[5];            // 128
  const int CIN_ = in_sizes[4]/C_;         // 64
  const int N    = in_sizes[0]/CIN_;       // 32768
  const int E    = in_sizes[1]/2;          // 524288
  const int B_   = in_sizes[3]-1;          // 32
  const int NPG_ = N/B_;                   // 1024
  const int K1_  = in_sizes[13];           // 128
  const int K2_  = in_sizes[23];           // 32
  const int OUTc = in_sizes[25];           // 10
  const int M2   = B_*K1_;                 // 4096

  const int* srcI = ei;
  const int* dstI = ei + E;

  float* ws = (float*)d_ws;
  size_t o = 0;
  float* dinv  = ws + o; o += (size_t)N;
  float* bufW  = ws + o; o += (size_t)N*C_;
  float* bufA  = ws + o; o += (size_t)N*C_;
  float* bufB  = ws + o; o += (size_t)N*C_;
  float* x2    = ws + o; o += (size_t)M2*C_;
  float* A2    = ws + o; o += (size_t)M2*K1_;
  float* dinv2 = ws + o; o += (size_t)M2;
  float* gsum  = ws + o; o += (size_t)C_;
  float* gsqs  = ws + o; o += (size_t)C_;
  // partials region (32MB) aliased with dense-stage scratch (used after pools complete)
  float* part  = ws + o; o += (size_t)KSPLIT*M2*C_;
  float* dW  = part;
  float* dT  = part + (size_t)M2*C_;
  float* h2a = part + 2*(size_t)M2*C_;
  float* h2b = part + 3*(size_t)M2*C_;
  int* degi    = (int*)(ws + o); o += (size_t)N;
  int* offs    = (int*)(ws + o); o += (size_t)N + 1;
  int* cursor  = (int*)(ws + o); o += (size_t)N;
  int* esrc    = (int*)(ws + o); o += (size_t)E;
  (void)ws_size; (void)n_in;

  dim3 blk256(256);
  dim3 gblk(16,16);
  auto g1 = [](int n){ return dim3((unsigned)((n+255)/256)); };

  // ---- CSR build ----
  hipMemsetAsync(degi, 0, (size_t)N*sizeof(int), stream);
  hipMemsetAsync(cursor, 0, (size_t)N*sizeof(int), stream);
  k_count_deg_i<<<g1(E), blk256, 0, stream>>>(dstI, degi, E);
  k_make_dinv<<<g1(N), blk256, 0, stream>>>(degi, dinv, N);
  k_scan<<<dim3(1), dim3(1024), 0, stream>>>(degi, offs, N);
  k_fill<<<g1(E), blk256, 0, stream>>>(srcI, dstI, cursor, offs, esrc, E);

  // ---- layer 1a ----
  k_gemm2<<<dim3(C_/128, N/128), blk256, 0, stream>>>(x, w1a, bufW, N, CIN_, C_, dinv);
  k_gather_gcn<false><<<dim3((unsigned)N), dim3(128), 0, stream>>>(offs, esrc, dinv, bufW, b1a, bufA);
  hipMemsetAsync(gsum, 0, 2*(size_t)C_*sizeof(float), stream);
  k_bn_stats<<<dim3(256), blk256, 0, stream>>>(bufA, gsum, gsqs, N*C_);
  k_bn_apply<<<g1(N*C_), blk256, 0, stream>>>(bufA, nullptr, gsum, gsqs, g1a, be1a, bufA, N*C_, 1.0f/N);

  // ---- layer 1b (residual) ----
  k_gemm2<<<dim3(C_/128, N/128), blk256, 0, stream>>>(bufA, w1b, bufW, N, C_, C_, dinv);
  k_gather_gcn<false><<<dim3((unsigned)N), dim3(128), 0, stream>>>(offs, esrc, dinv, bufW, b1b, bufB);
  hipMemsetAsync(gsum, 0, 2*(size_t)C_*sizeof(float), stream);
  k_bn_stats<<<dim3(256), blk256, 0, stream>>>(bufB, gsum, gsqs, N*C_);
  k_bn_apply<<<g1(N*C_), blk256, 0, stream>>>(bufB, bufA, gsum, gsqs, g1b, be1b, bufB, N*C_, 1.0f/N);

  // ---- pool: s = softmax(gcn(hB, wp1, bp1)) ----
  k_gemm2<<<dim3(K1_/128, N/128), blk256, 0, stream>>>(bufB, wp1, bufW, N, C_, K1_, dinv);
  k_gather_gcn<true><<<dim3((unsigned)N), dim3(128), 0, stream>>>(offs, esrc, dinv, bufW, bp1, bufA);

  // t = A s (raw adjacency)
  k_gather_sum<<<dim3((unsigned)N), dim3(128), 0, stream>>>(offs, esrc, bufA, bufW);

  // x2 = s^T h ; A2 = s^T t  (split-K partials + reduce)
  const int total = M2*C_;   // 524288
  k_pool_split<<<dim3(KSPLIT, B_), blk256, 0, stream>>>(bufA, bufB, part, NPG_);
  k_pool_reduce<<<g1(total/4), blk256, 0, stream>>>(part, x2, total);
  k_pool_split<<<dim3(KSPLIT, B_), blk256, 0, stream>>>(bufA, bufW, part, NPG_);
  k_pool_reduce<<<g1(total/4), blk256, 0, stream>>>(part, A2, total);

  // ---- dense stage ----
  k_dinv2<<<dim3((unsigned)M2), dim3(128), 0, stream>>>(A2, dinv2, M2);

  // layer 2a
  k_gemm<<<dim3(C_/64, M2/64), gblk, 0, stream>>>(x2, w2a, dW, M2, C_, C_, dinv2);
  k_bgemm<<<dim3(C_/16, K1_/16, B_), gblk, 0, stream>>>(A2, dW, dT);
  k_dense_post<<<g1(M2*C_), blk256, 0, stream>>>(dT, dW, dinv2, b2a, M2*C_);
  hipMemsetAsync(gsum, 0, 2*(size_t)C_*sizeof(float), stream);
  k_bn_stats<<<dim3(64), blk256, 0, stream>>>(dT, gsum, gsqs, M2*C_);
  k_bn_apply<<<g1(M2*C_), blk256, 0, stream>>>(dT, nullptr, gsum, gsqs, g2a, be2a, h2a, M2*C_, 1.0f/M2);

  // layer 2b (residual)
  k_gemm<<<dim3(C_/64, M2/64), gblk, 0, stream>>>(h2a, w2b, dW, M2, C_, C_, dinv2);
  k_bgemm<<<dim3(C_/16, K1_/16, B_), gblk, 0, stream>>>(A2, dW, dT);
  k_dense_post<<<g1(M2*C_), blk256, 0, stream>>>(dT, dW, dinv2, b2b, M2*C_);
  hipMemsetAsync(gsum, 0, 2*(size_t)C_*sizeof(float), stream);
  k_bn_stats<<<dim3(64), blk256, 0, stream>>>(dT, gsum, gsqs, M2*C_);
  k_bn_apply<<<g1(M2*C_), blk256, 0, stream>>>(dT, h2a, gsum, gsqs, g2b, be2b, h2b, M2*C_, 1.0f/M2);

  // ---- final ----
  int zero_idx = (out_size > B_*OUTc) ? B_*OUTc : -1;
  k_final<<<dim3((unsigned)B_), dim3(128), 0, stream>>>(h2b, wl, bl, out, K1_, C_, OUTc, 1.0f/K2_, zero_idx);
}